// Round 7
// baseline (2650.786 us; speedup 1.0000x reference)
//
#include <hip/hip_runtime.h>
#include <hip/hip_bf16.h>
#include <cmath>

#define T_STEPS 50
#define BATCH   8192
#define ROWS    64                 // rows per block
#define NBLK    (BATCH / ROWS)     // 128 blocks
#define THREADS 1024               // 16 waves; one N-tile per wave, 4 M-tiles each
#define MT      4                  // M-tiles (16 rows each)

typedef float  f32x4  __attribute__((ext_vector_type(4)));
typedef __bf16 bf16x8 __attribute__((ext_vector_type(8)));
typedef unsigned short u16x4 __attribute__((ext_vector_type(4)));

// ---- packed weight regions in d_ws (bf16), padded to 16 N-tiles ----
// B-frag layout: [ntile][kstep][lane(64)][8]; n = nt*16 + (lane&15), k = ks*32 + (lane>>4)*8 + e
#define N_FC   (16*2*512)
#define N_R    (16*14*512)
#define N_Z    (16*14*512)
#define N_IN   (16*7*512)
#define N_HN   (16*7*512)
#define N_W1   (16*7*512)
#define N_MV   (4*7*512)
#define OFF_FC 0
#define OFF_R  (OFF_FC + N_FC)
#define OFF_Z  (OFF_R  + N_R)
#define OFF_IN (OFF_Z  + N_Z)
#define OFF_HN (OFF_IN + N_IN)
#define OFF_W1 (OFF_HN + N_HN)
#define OFF_MV (OFF_W1 + N_W1)
#define W_TOTAL (OFF_MV + N_MV)    // 432128 elems = 864 KB

__device__ __forceinline__ unsigned short f2b(float f) {
    union { float f; unsigned u; } v; v.f = f;
    unsigned r = v.u + 0x7FFFu + ((v.u >> 16) & 1u);
    return (unsigned short)(r >> 16);
}
__device__ __forceinline__ float b2f(unsigned short h) {
    union { unsigned u; float f; } v; v.u = ((unsigned)h) << 16;
    return v.f;
}
__device__ __forceinline__ int fragSlot(int row, int k) {
    int sub = k & 31;
    return ((((sub >> 3) & 3) << 4) | row) * 8 + (sub & 7);
}
__device__ __forceinline__ f32x4 MFMA(bf16x8 a, bf16x8 b, f32x4 c) {
    return __builtin_amdgcn_mfma_f32_16x16x32_bf16(a, b, c, 0, 0, 0);
}
__device__ __forceinline__ float sigmf(float x) { return 1.f / (1.f + __expf(-x)); }
__device__ __forceinline__ float tanh_fast(float x) {
    float e = __expf(2.f * fminf(x, 40.f));
    return (e - 1.f) / (e + 1.f);
}
__device__ __forceinline__ void st_nt4(float* p, f32x4 v) {
    __builtin_nontemporal_store(v, reinterpret_cast<f32x4*>(p));
}
__device__ __forceinline__ float ld_nt(const float* p) { return __builtin_nontemporal_load(p); }

// ================= weight prep: fp32 -> bf16, padded to 16 tiles, fragment-ordered =================
__global__ void rssm_prep(const float* __restrict__ Wfc, const float* __restrict__ Wih,
                          const float* __restrict__ Whh, const float* __restrict__ W1,
                          const float* __restrict__ Wmu, const float* __restrict__ Wvar,
                          unsigned short* __restrict__ out)
{
    int idx = blockIdx.x * 256 + threadIdx.x;
    if (idx >= W_TOTAL) return;
    float v = 0.f;
    if (idx < OFF_R) {                        // FC: [16][2][512], W_fc [200,36]
        int loc = idx - OFF_FC;
        int nt = loc / (2 * 512), r = loc % (2 * 512), ks = r / 512, li = r % 512;
        int lane = li >> 3, e = li & 7;
        int n = nt * 16 + (lane & 15);
        int k = ks * 32 + (lane >> 4) * 8 + e;
        if (n < 200 && k < 36) v = Wfc[n * 36 + k];
    } else if (idx < OFF_Z) {                 // R gate: K = x(0..223)|h(224..447)
        int loc = idx - OFF_R;
        int nt = loc / (14 * 512), r = loc % (14 * 512), ks = r / 512, li = r % 512;
        int lane = li >> 3, e = li & 7;
        int n = nt * 16 + (lane & 15);
        int k = ks * 32 + (lane >> 4) * 8 + e;
        if (n < 200) {
            if (k < 224) { if (k < 200) v = Wih[n * 200 + k]; }
            else { int kk = k - 224; if (kk < 200) v = Whh[n * 200 + kk]; }
        }
    } else if (idx < OFF_IN) {                // Z gate
        int loc = idx - OFF_Z;
        int nt = loc / (14 * 512), r = loc % (14 * 512), ks = r / 512, li = r % 512;
        int lane = li >> 3, e = li & 7;
        int n = nt * 16 + (lane & 15);
        int k = ks * 32 + (lane >> 4) * 8 + e;
        if (n < 200) {
            if (k < 224) { if (k < 200) v = Wih[(200 + n) * 200 + k]; }
            else { int kk = k - 224; if (kk < 200) v = Whh[(200 + n) * 200 + kk]; }
        }
    } else if (idx < OFF_HN) {                // IN: n-gate of W_ih
        int loc = idx - OFF_IN;
        int nt = loc / (7 * 512), r = loc % (7 * 512), ks = r / 512, li = r % 512;
        int lane = li >> 3, e = li & 7;
        int n = nt * 16 + (lane & 15);
        int k = ks * 32 + (lane >> 4) * 8 + e;
        if (n < 200 && k < 200) v = Wih[(400 + n) * 200 + k];
    } else if (idx < OFF_W1) {                // HN: n-gate of W_hh
        int loc = idx - OFF_HN;
        int nt = loc / (7 * 512), r = loc % (7 * 512), ks = r / 512, li = r % 512;
        int lane = li >> 3, e = li & 7;
        int n = nt * 16 + (lane & 15);
        int k = ks * 32 + (lane >> 4) * 8 + e;
        if (n < 200 && k < 200) v = Whh[(400 + n) * 200 + k];
    } else if (idx < OFF_MV) {                // W1
        int loc = idx - OFF_W1;
        int nt = loc / (7 * 512), r = loc % (7 * 512), ks = r / 512, li = r % 512;
        int lane = li >> 3, e = li & 7;
        int n = nt * 16 + (lane & 15);
        int k = ks * 32 + (lane >> 4) * 8 + e;
        if (n < 200 && k < 200) v = W1[n * 200 + k];
    } else {                                  // MV: nt 0-1 mu rows, nt 2-3 var rows
        int loc = idx - OFF_MV;
        int nt = loc / (7 * 512), r = loc % (7 * 512), ks = r / 512, li = r % 512;
        int lane = li >> 3, e = li & 7;
        int k = ks * 32 + (lane >> 4) * 8 + e;
        if (nt < 2) { int m = nt * 16 + (lane & 15); if (m < 30 && k < 200) v = Wmu[m * 200 + k]; }
        else        { int m = (nt - 2) * 16 + (lane & 15); if (m < 30 && k < 200) v = Wvar[m * 200 + k]; }
    }
    out[idx] = f2b(v);
}

// ================= main kernel: 128 blocks x 64 rows, 16 waves =================
__global__ __launch_bounds__(THREADS, 4) void rssm_main(
    const float* __restrict__ actions, const float* __restrict__ h0,
    const float* __restrict__ s0, const float* __restrict__ noise,
    const float* __restrict__ b_fc, const float* __restrict__ b_ih,
    const float* __restrict__ b_hh, const float* __restrict__ b1,
    const float* __restrict__ bmu, const float* __restrict__ bvar,
    const unsigned short* __restrict__ W, float* __restrict__ out)
{
    // Activation buffers, MFMA A-fragment layout [mt][ks][512] (mt in 0..3)
    __shared__ __align__(16) unsigned short Xb[MT * 7 * 512];         // x, k 0..223     28672 B
    __shared__ __align__(16) unsigned short Hb[2][MT * 7 * 512];      // h ping-pong     57344 B
    __shared__ __align__(16) unsigned short HIDb[MT * 7 * 512];       // hidden          28672 B
    __shared__ __align__(16) unsigned short SAb[MT * 2 * 512];        // s|a, k 0..35     8192 B
    __shared__ __align__(16) unsigned short STG_S[ROWS * 200];        // states (bf16)   25600 B
    __shared__ __align__(16) float          STG_Z[ROWS * 30];         // stoch (fp32)     7680 B
    // total 156160 B

    const int tid = threadIdx.x;
    const int w = tid >> 6, lane = tid & 63;
    const int col = lane & 15, kg = lane >> 4;
    const int brow0 = blockIdx.x * ROWS;
    const int jt = w;                          // tiles 0..12 active, 13..15 pad
    const bool active = (jt < 13);
    const int j = jt * 16 + col;
    const bool jv = (j < 200);

    const unsigned short* WFC = W + OFF_FC;
    const unsigned short* WRr = W + OFF_R;
    const unsigned short* WZr = W + OFF_Z;
    const unsigned short* WIN = W + OFF_IN;
    const unsigned short* WHN = W + OFF_HN;
    const unsigned short* W1w = W + OFF_W1;
    const unsigned short* WMV = W + OFF_MV;
    float* out_states = out;
    float* out_stoch  = out + (size_t)T_STEPS * BATCH * 200;

    // ---- hoisted per-thread biases ----
    float bfcv = 0.f, brv = 0.f, bzv = 0.f, biv = 0.f, bhv = 0.f, b1v = 0.f;
    if (jv) {
        bfcv = b_fc[j];
        brv = b_ih[j] + b_hh[j];
        bzv = b_ih[200 + j] + b_hh[200 + j];
        biv = b_ih[400 + j];
        bhv = b_hh[400 + j];
        b1v = b1[j];
    }
    float bmuv = 0.f, bvav = 0.f;
    if (w < 8) {
        const int jm = (w & 1) * 16 + col;
        if (jm < 30) { bmuv = bmu[jm]; bvav = bvar[jm]; }
    }

    // ---- init: zero LDS (pad slots must be 0), load h0/s0/a0 ----
    for (int i = tid; i < MT * 7 * 512; i += THREADS) Xb[i] = 0;
    for (int i = tid; i < MT * 7 * 512; i += THREADS) { Hb[0][i] = 0; Hb[1][i] = 0; }
    for (int i = tid; i < MT * 7 * 512; i += THREADS) HIDb[i] = 0;
    for (int i = tid; i < MT * 2 * 512; i += THREADS) SAb[i] = 0;
    __syncthreads();
    for (int i = tid; i < ROWS * 200; i += THREADS) {
        int r = i / 200, jj = i % 200;
        Hb[0][((r >> 4) * 7 + (jj >> 5)) * 512 + fragSlot(r & 15, jj)] =
            f2b(h0[(size_t)(brow0 + r) * 200 + jj]);
    }
    for (int i = tid; i < ROWS * 30; i += THREADS) {
        int r = i / 30, jj = i % 30;
        SAb[((r >> 4) * 2) * 512 + fragSlot(r & 15, jj)] =
            f2b(s0[(size_t)(brow0 + r) * 30 + jj]);
    }
    for (int i = tid; i < ROWS * 6; i += THREADS) {
        int r = i / 6, c = i % 6, k = 30 + c;
        SAb[((r >> 4) * 2 + (k >> 5)) * 512 + fragSlot(r & 15, k)] =
            f2b(ld_nt(&actions[(size_t)(brow0 + r) * 6 + c]));
    }
    __syncthreads();

    for (int t = 0; t < T_STEPS; ++t) {
        const int cur = t & 1, nxt = cur ^ 1;

        // ---------- Phase 1: x = FC(concat(s,a)) -> Xb ; pad waves drain stoch(t-1) ----------
        if (active) {
            f32x4 c[MT];
            #pragma unroll
            for (int mt = 0; mt < MT; ++mt) c[mt] = (f32x4){0.f,0.f,0.f,0.f};
            #pragma unroll
            for (int ks = 0; ks < 2; ++ks) {
                bf16x8 b = *reinterpret_cast<const bf16x8*>(&WFC[(size_t)(jt * 2 + ks) * 512 + lane * 8]);
                #pragma unroll
                for (int mt = 0; mt < MT; ++mt) {
                    bf16x8 a = *reinterpret_cast<const bf16x8*>(&SAb[(mt * 2 + ks) * 512 + lane * 8]);
                    c[mt] = MFMA(a, b, c[mt]);
                }
            }
            #pragma unroll
            for (int mt = 0; mt < MT; ++mt)
                #pragma unroll
                for (int q = 0; q < 4; ++q)
                    Xb[(mt * 7 + (j >> 5)) * 512 + fragSlot(kg * 4 + q, j)] = f2b(c[mt][q] + bfcv);
        } else if (t >= 1) {
            const int di = (jt - 13) * 64 + lane;   // 0..191
            float* dst = out_stoch + ((size_t)(t - 1) * BATCH + brow0) * 30;
            for (int i = di; i < 480; i += 192) {
                f32x4 v = *reinterpret_cast<const f32x4*>(&STG_Z[i * 4]);
                st_nt4(dst + i * 4, v);
            }
        }
        __syncthreads();

        // ---------- Phase 2: gates in 3 passes (RZ, Ni, Nh); h_new -> Hb[nxt] + STG_S ----------
        if (active) {
            f32x4 aR[MT], aZ[MT];
            #pragma unroll
            for (int mt = 0; mt < MT; ++mt) {
                aR[mt] = (f32x4){0.f,0.f,0.f,0.f};
                aZ[mt] = (f32x4){0.f,0.f,0.f,0.f};
            }
            #pragma unroll
            for (int ks = 0; ks < 14; ++ks) {
                bf16x8 bR = *reinterpret_cast<const bf16x8*>(&WRr[(size_t)(jt * 14 + ks) * 512 + lane * 8]);
                bf16x8 bZ = *reinterpret_cast<const bf16x8*>(&WZr[(size_t)(jt * 14 + ks) * 512 + lane * 8]);
                #pragma unroll
                for (int mt = 0; mt < MT; ++mt) {
                    bf16x8 a = (ks < 7)
                        ? *reinterpret_cast<const bf16x8*>(&Xb[(mt * 7 + ks) * 512 + lane * 8])
                        : *reinterpret_cast<const bf16x8*>(&Hb[cur][(mt * 7 + (ks - 7)) * 512 + lane * 8]);
                    aR[mt] = MFMA(a, bR, aR[mt]);
                    aZ[mt] = MFMA(a, bZ, aZ[mt]);
                }
            }
            float rg[MT][4], zg[MT][4];
            #pragma unroll
            for (int mt = 0; mt < MT; ++mt)
                #pragma unroll
                for (int q = 0; q < 4; ++q) {
                    rg[mt][q] = sigmf(aR[mt][q] + brv);
                    zg[mt][q] = sigmf(aZ[mt][q] + bzv);
                }
            f32x4 aNi[MT];
            #pragma unroll
            for (int mt = 0; mt < MT; ++mt) aNi[mt] = (f32x4){0.f,0.f,0.f,0.f};
            #pragma unroll
            for (int ks = 0; ks < 7; ++ks) {
                bf16x8 b = *reinterpret_cast<const bf16x8*>(&WIN[(size_t)(jt * 7 + ks) * 512 + lane * 8]);
                #pragma unroll
                for (int mt = 0; mt < MT; ++mt) {
                    bf16x8 a = *reinterpret_cast<const bf16x8*>(&Xb[(mt * 7 + ks) * 512 + lane * 8]);
                    aNi[mt] = MFMA(a, b, aNi[mt]);
                }
            }
            f32x4 aNh[MT];
            #pragma unroll
            for (int mt = 0; mt < MT; ++mt) aNh[mt] = (f32x4){0.f,0.f,0.f,0.f};
            #pragma unroll
            for (int ks = 0; ks < 7; ++ks) {
                bf16x8 b = *reinterpret_cast<const bf16x8*>(&WHN[(size_t)(jt * 7 + ks) * 512 + lane * 8]);
                #pragma unroll
                for (int mt = 0; mt < MT; ++mt) {
                    bf16x8 a = *reinterpret_cast<const bf16x8*>(&Hb[cur][(mt * 7 + ks) * 512 + lane * 8]);
                    aNh[mt] = MFMA(a, b, aNh[mt]);
                }
            }
            #pragma unroll
            for (int mt = 0; mt < MT; ++mt) {
                #pragma unroll
                for (int q = 0; q < 4; ++q) {
                    const int r0 = kg * 4 + q;
                    const int slot = (j >> 5) * 512 + fragSlot(r0, j);
                    float ng = tanh_fast((aNi[mt][q] + biv) + rg[mt][q] * (aNh[mt][q] + bhv));
                    if (jv) {
                        float hv = b2f(Hb[cur][mt * 7 * 512 + slot]);
                        float hn = (1.f - zg[mt][q]) * ng + zg[mt][q] * hv;
                        unsigned short hb = f2b(hn);
                        Hb[nxt][mt * 7 * 512 + slot] = hb;
                        STG_S[(mt * 16 + r0) * 200 + j] = hb;
                    }
                }
            }
        }
        __syncthreads();

        // ---------- Phase 3: hid = relu(h_new @ W1^T + b1) -> HIDb ----------
        if (active) {
            f32x4 c[MT];
            #pragma unroll
            for (int mt = 0; mt < MT; ++mt) c[mt] = (f32x4){0.f,0.f,0.f,0.f};
            #pragma unroll
            for (int ks = 0; ks < 7; ++ks) {
                bf16x8 b = *reinterpret_cast<const bf16x8*>(&W1w[(size_t)(jt * 7 + ks) * 512 + lane * 8]);
                #pragma unroll
                for (int mt = 0; mt < MT; ++mt) {
                    bf16x8 a = *reinterpret_cast<const bf16x8*>(&Hb[nxt][(mt * 7 + ks) * 512 + lane * 8]);
                    c[mt] = MFMA(a, b, c[mt]);
                }
            }
            #pragma unroll
            for (int mt = 0; mt < MT; ++mt)
                #pragma unroll
                for (int q = 0; q < 4; ++q)
                    HIDb[(mt * 7 + (j >> 5)) * 512 + fragSlot(kg * 4 + q, j)] =
                        f2b(fmaxf(c[mt][q] + b1v, 0.f));
        }
        __syncthreads();

        // ---------- Phase 4: waves 0-7 mu/var -> s_new ; waves 8-15 drain states + prefetch a ----------
        if (w < 8) {
            const int mt = w >> 1, ntile = w & 1;
            f32x4 cm = {0.f,0.f,0.f,0.f}, cv = {0.f,0.f,0.f,0.f};
            #pragma unroll
            for (int ks = 0; ks < 7; ++ks) {
                bf16x8 a  = *reinterpret_cast<const bf16x8*>(&HIDb[(mt * 7 + ks) * 512 + lane * 8]);
                bf16x8 bm = *reinterpret_cast<const bf16x8*>(&WMV[(size_t)(ntile * 7 + ks) * 512 + lane * 8]);
                bf16x8 bv = *reinterpret_cast<const bf16x8*>(&WMV[(size_t)((2 + ntile) * 7 + ks) * 512 + lane * 8]);
                cm = MFMA(a, bm, cm);
                cv = MFMA(a, bv, cv);
            }
            const int jm = ntile * 16 + col;
            const bool jmv = (jm < 30);
            #pragma unroll
            for (int q = 0; q < 4; ++q) {
                const int r0 = kg * 4 + q;
                const int row = mt * 16 + r0;
                float mu = cm[q] + bmuv;
                float vr = cv[q] + bvav;
                float var = ((vr > 20.f) ? vr : log1pf(__expf(vr))) + 0.1f;
                if (jmv) {
                    float eps = ld_nt(&noise[((size_t)t * BATCH + brow0 + row) * 30 + jm]);
                    float sn = mu + var * eps;
                    STG_Z[row * 30 + jm] = sn;
                    SAb[(mt * 2) * 512 + fragSlot(r0, jm)] = f2b(sn);
                }
            }
        } else {
            const int di = (w - 8) * 64 + lane;   // 0..511
            // drain states(t): 64*200 bf16 -> fp32 full-line nt stores (3200 float4)
            float* dst = out_states + ((size_t)t * BATCH + brow0) * 200;
            for (int i = di; i < 3200; i += 512) {
                u16x4 hv4 = *reinterpret_cast<const u16x4*>(&STG_S[i * 4]);
                f32x4 v;
                v[0] = b2f(hv4[0]); v[1] = b2f(hv4[1]);
                v[2] = b2f(hv4[2]); v[3] = b2f(hv4[3]);
                st_nt4(dst + i * 4, v);
            }
            // prefetch actions(t+1)
            if (t + 1 < T_STEPS && di < ROWS * 6) {
                const int r = di / 6, c = di % 6, k = 30 + c;
                float av = ld_nt(&actions[((size_t)(t + 1) * BATCH + brow0 + r) * 6 + c]);
                SAb[((r >> 4) * 2 + (k >> 5)) * 512 + fragSlot(r & 15, k)] = f2b(av);
            }
        }
        __syncthreads();
    }

    // drain stoch(T-1)
    if (tid < 480) {
        f32x4 v = *reinterpret_cast<const f32x4*>(&STG_Z[tid * 4]);
        st_nt4(out_stoch + ((size_t)(T_STEPS - 1) * BATCH + brow0) * 30 + tid * 4, v);
    }
}

extern "C" void kernel_launch(void* const* d_in, const int* in_sizes, int n_in,
                              void* d_out, int out_size, void* d_ws, size_t ws_size,
                              hipStream_t stream)
{
    const float* actions = (const float*)d_in[0];
    const float* h0      = (const float*)d_in[1];
    const float* s0      = (const float*)d_in[2];
    const float* noise   = (const float*)d_in[3];
    const float* Wfc     = (const float*)d_in[4];
    const float* bfc     = (const float*)d_in[5];
    const float* Wih     = (const float*)d_in[6];
    const float* bih     = (const float*)d_in[7];
    const float* Whh     = (const float*)d_in[8];
    const float* bhh     = (const float*)d_in[9];
    const float* W1      = (const float*)d_in[10];
    const float* b1      = (const float*)d_in[11];
    const float* Wmu     = (const float*)d_in[12];
    const float* bmu     = (const float*)d_in[13];
    const float* Wvar    = (const float*)d_in[14];
    const float* bvar    = (const float*)d_in[15];

    unsigned short* wbuf = (unsigned short*)d_ws;

    rssm_prep<<<(W_TOTAL + 255) / 256, 256, 0, stream>>>(Wfc, Wih, Whh, W1, Wmu, Wvar, wbuf);
    rssm_main<<<NBLK, THREADS, 0, stream>>>(actions, h0, s0, noise, bfc, bih, bhh, b1,
                                            bmu, bvar, wbuf, (float*)d_out);
}

// Round 8
// 1258.151 us; speedup vs baseline: 2.1069x; 2.1069x over previous
//
#include <hip/hip_runtime.h>
#include <hip/hip_bf16.h>
#include <cmath>

#define T_STEPS 50
#define BATCH   8192
#define ROWS    32                 // rows per block
#define NBLK    (BATCH / ROWS)     // 256 blocks
#define THREADS 512                // 8 waves

typedef float  f32x4  __attribute__((ext_vector_type(4)));
typedef __bf16 bf16x8 __attribute__((ext_vector_type(8)));

// ---- packed weight regions in d_ws (bf16), FC composed into gates ----
// B-frag layout: [ntile][kstep][lane(64)][8]; n = nt*16+(lane&15), k = ks*32+(lane>>4)*8+e
// Gate K-space (R/Z): ks0-1 = [s(0..29)|a(30..35)|pad], ks2-8 = h(k-64 in 0..223)
#define N_R9   (13*9*512)
#define N_NI   (13*2*512)
#define N_NH   (13*7*512)
#define N_W1   (13*7*512)
#define N_MV   (4*7*512)
#define OFF_R  0
#define OFF_Z  (OFF_R  + N_R9)     // 59904
#define OFF_NI (OFF_Z  + N_R9)     // 119808
#define OFF_NH (OFF_NI + N_NI)     // 133120
#define OFF_W1 (OFF_NH + N_NH)     // 179712
#define OFF_MV (OFF_W1 + N_W1)     // 226304
#define W_TOTAL (OFF_MV + N_MV)    // 240640 elems = 481 KB

__device__ __forceinline__ unsigned short f2b(float f) {
    union { float f; unsigned u; } v; v.f = f;
    unsigned r = v.u + 0x7FFFu + ((v.u >> 16) & 1u);
    return (unsigned short)(r >> 16);
}
__device__ __forceinline__ float b2f(unsigned short h) {
    union { unsigned u; float f; } v; v.u = ((unsigned)h) << 16;
    return v.f;
}
__device__ __forceinline__ int fragSlot(int row, int k) {
    int sub = k & 31;
    return ((((sub >> 3) & 3) << 4) | row) * 8 + (sub & 7);
}
__device__ __forceinline__ f32x4 MFMA(bf16x8 a, bf16x8 b, f32x4 c) {
    return __builtin_amdgcn_mfma_f32_16x16x32_bf16(a, b, c, 0, 0, 0);
}
__device__ __forceinline__ float sigmf(float x) { return 1.f / (1.f + __expf(-x)); }
__device__ __forceinline__ float tanh_fast(float x) {
    float e = __expf(2.f * fminf(x, 40.f));
    return (e - 1.f) / (e + 1.f);
}
__device__ __forceinline__ void st_nt4(float* p, f32x4 v) {
    __builtin_nontemporal_store(v, reinterpret_cast<f32x4*>(p));
}
__device__ __forceinline__ float ld_nt(const float* p) { return __builtin_nontemporal_load(p); }

// ================= weight prep: compose FC into gates, fp32 -> bf16, fragment-ordered =================
__global__ void rssm_prep(const float* __restrict__ Wfc, const float* __restrict__ Wih,
                          const float* __restrict__ Whh, const float* __restrict__ W1,
                          const float* __restrict__ Wmu, const float* __restrict__ Wvar,
                          unsigned short* __restrict__ out)
{
    int idx = blockIdx.x * 256 + threadIdx.x;
    if (idx >= W_TOTAL) return;
    float v = 0.f;
    if (idx < OFF_NI) {                       // R (idx<OFF_Z) or Z gate: [13][9][512]
        const int base = (idx < OFF_Z) ? OFF_R : OFF_Z;
        const int grow = (idx < OFF_Z) ? 0 : 200;   // gate row offset in W_ih/W_hh
        int loc = idx - base;
        int nt = loc / (9 * 512), r = loc % (9 * 512), ks = r / 512, li = r % 512;
        int lane = li >> 3, e = li & 7;
        int n = nt * 16 + (lane & 15);
        int k = ks * 32 + (lane >> 4) * 8 + e;
        if (n < 200) {
            if (k < 36) {                      // composed: (W_ih,g . W_fc)[n,k]
                float acc = 0.f;
                for (int m = 0; m < 200; ++m)
                    acc += Wih[(grow + n) * 200 + m] * Wfc[m * 36 + k];
                v = acc;
            } else if (k >= 64 && (k - 64) < 200) {
                v = Whh[(grow + n) * 200 + (k - 64)];
            }
        }
    } else if (idx < OFF_NH) {                // NI: composed n-gate sa part [13][2][512]
        int loc = idx - OFF_NI;
        int nt = loc / (2 * 512), r = loc % (2 * 512), ks = r / 512, li = r % 512;
        int lane = li >> 3, e = li & 7;
        int n = nt * 16 + (lane & 15);
        int k = ks * 32 + (lane >> 4) * 8 + e;
        if (n < 200 && k < 36) {
            float acc = 0.f;
            for (int m = 0; m < 200; ++m)
                acc += Wih[(400 + n) * 200 + m] * Wfc[m * 36 + k];
            v = acc;
        }
    } else if (idx < OFF_W1) {                // NH: n-gate of W_hh [13][7][512]
        int loc = idx - OFF_NH;
        int nt = loc / (7 * 512), r = loc % (7 * 512), ks = r / 512, li = r % 512;
        int lane = li >> 3, e = li & 7;
        int n = nt * 16 + (lane & 15);
        int k = ks * 32 + (lane >> 4) * 8 + e;
        if (n < 200 && k < 200) v = Whh[(400 + n) * 200 + k];
    } else if (idx < OFF_MV) {                // W1 [13][7][512]
        int loc = idx - OFF_W1;
        int nt = loc / (7 * 512), r = loc % (7 * 512), ks = r / 512, li = r % 512;
        int lane = li >> 3, e = li & 7;
        int n = nt * 16 + (lane & 15);
        int k = ks * 32 + (lane >> 4) * 8 + e;
        if (n < 200 && k < 200) v = W1[n * 200 + k];
    } else {                                  // MV [4][7][512]: nt 0-1 mu, 2-3 var
        int loc = idx - OFF_MV;
        int nt = loc / (7 * 512), r = loc % (7 * 512), ks = r / 512, li = r % 512;
        int lane = li >> 3, e = li & 7;
        int k = ks * 32 + (lane >> 4) * 8 + e;
        if (nt < 2) { int m = nt * 16 + (lane & 15); if (m < 30 && k < 200) v = Wmu[m * 200 + k]; }
        else        { int m = (nt - 2) * 16 + (lane & 15); if (m < 30 && k < 200) v = Wvar[m * 200 + k]; }
    }
    out[idx] = f2b(v);
}

// ================= main kernel: 256 blocks x 32 rows, 8 waves, 3 phases/step =================
__global__ __launch_bounds__(THREADS, 2) void rssm_main(
    const float* __restrict__ actions, const float* __restrict__ h0,
    const float* __restrict__ s0, const float* __restrict__ noise,
    const float* __restrict__ Wih_f32, const float* __restrict__ b_fc,
    const float* __restrict__ b_ih, const float* __restrict__ b_hh,
    const float* __restrict__ b1, const float* __restrict__ bmu,
    const float* __restrict__ bvar, const unsigned short* __restrict__ W,
    float* __restrict__ out)
{
    // Activation buffers, MFMA A-fragment layout [mt][ks][512] (mt in 0..1)
    __shared__ __align__(16) unsigned short Hb[2][2 * 7 * 512];     // h ping-pong  28672 B
    __shared__ __align__(16) unsigned short HIDb[2 * 7 * 512];      // hidden       14336 B
    __shared__ __align__(16) unsigned short SAb[2 * 2 * 512];       // s|a k0..35    4096 B
    __shared__ __align__(16) float STG_S[ROWS * 200];               // states fp32  25600 B
    __shared__ __align__(16) float STG_Z[2][ROWS * 30];             // stoch fp32    7680 B
    // total 80384 B

    const int tid = threadIdx.x;
    const int w = tid >> 6, lane = tid & 63;
    const int col = lane & 15, kg = lane >> 4;
    const int brow0 = blockIdx.x * ROWS;
    const int jt0 = w;
    const int jt1 = (w < 5) ? (w + 8) : -1;    // 13 tiles over 8 waves

    const unsigned short* WR  = W + OFF_R;
    const unsigned short* WZ  = W + OFF_Z;
    const unsigned short* WNI = W + OFF_NI;
    const unsigned short* WNH = W + OFF_NH;
    const unsigned short* W1w = W + OFF_W1;
    const unsigned short* WMV = W + OFF_MV;
    float* out_states = out;
    float* out_stoch  = out + (size_t)T_STEPS * BATCH * 200;

    // ---- composed per-thread biases (once; 200-FMA loops) ----
    float brv[2] = {0.f, 0.f}, bzv[2] = {0.f, 0.f}, biv[2] = {0.f, 0.f};
    float bhv[2] = {0.f, 0.f}, b1v[2] = {0.f, 0.f};
    #pragma unroll
    for (int ji = 0; ji < 2; ++ji) {
        const int jt = ji ? jt1 : jt0;
        if (jt < 0) continue;
        const int j = jt * 16 + col;
        if (j < 200) {
            float aR = 0.f, aZ = 0.f, aN = 0.f;
            for (int m = 0; m < 200; ++m) {
                float bf = b_fc[m];
                aR += Wih_f32[j * 200 + m] * bf;
                aZ += Wih_f32[(200 + j) * 200 + m] * bf;
                aN += Wih_f32[(400 + j) * 200 + m] * bf;
            }
            brv[ji] = aR + b_ih[j] + b_hh[j];
            bzv[ji] = aZ + b_ih[200 + j] + b_hh[200 + j];
            biv[ji] = aN + b_ih[400 + j];
            bhv[ji] = b_hh[400 + j];
            b1v[ji] = b1[j];
        }
    }
    float bmuv = 0.f, bvav = 0.f;
    if (w < 4) {
        const int jm = (w & 1) * 16 + col;
        if (jm < 30) { bmuv = bmu[jm]; bvav = bvar[jm]; }
    }

    // ---- init: zero LDS (pad slots must be 0), load h0/s0/a0 ----
    for (int i = tid; i < 2 * 7 * 512; i += THREADS) { Hb[0][i] = 0; Hb[1][i] = 0; }
    for (int i = tid; i < 2 * 7 * 512; i += THREADS) HIDb[i] = 0;
    for (int i = tid; i < 2 * 2 * 512; i += THREADS) SAb[i] = 0;
    __syncthreads();
    for (int i = tid; i < ROWS * 200; i += THREADS) {
        int r = i / 200, jj = i % 200;
        Hb[0][((r >> 4) * 7 + (jj >> 5)) * 512 + fragSlot(r & 15, jj)] =
            f2b(h0[(size_t)(brow0 + r) * 200 + jj]);
    }
    for (int i = tid; i < ROWS * 30; i += THREADS) {
        int r = i / 30, jj = i % 30;
        SAb[((r >> 4) * 2) * 512 + fragSlot(r & 15, jj)] =
            f2b(s0[(size_t)(brow0 + r) * 30 + jj]);
    }
    for (int i = tid; i < ROWS * 6; i += THREADS) {
        int r = i / 6, c = i % 6, k = 30 + c;
        SAb[((r >> 4) * 2 + (k >> 5)) * 512 + fragSlot(r & 15, k)] =
            f2b(ld_nt(&actions[(size_t)(brow0 + r) * 6 + c]));
    }
    __syncthreads();

    for (int t = 0; t < T_STEPS; ++t) {
        const int cur = t & 1, nxt = cur ^ 1;

        // ---------- Phase A: gates over K=[s|a|pad|h]; h_new -> Hb[nxt] + STG_S ----------
        #pragma unroll
        for (int ji = 0; ji < 2; ++ji) {
            const int jt = ji ? jt1 : jt0;
            if (jt < 0) continue;
            // prefetch this tile's 27 weight frags (108 VGPR)
            bf16x8 wRr[9], wZr[9], wNi[2], wNh[7];
            #pragma unroll
            for (int ks = 0; ks < 9; ++ks) {
                wRr[ks] = *reinterpret_cast<const bf16x8*>(&WR[(size_t)(jt * 9 + ks) * 512 + lane * 8]);
                wZr[ks] = *reinterpret_cast<const bf16x8*>(&WZ[(size_t)(jt * 9 + ks) * 512 + lane * 8]);
            }
            #pragma unroll
            for (int ks = 0; ks < 2; ++ks)
                wNi[ks] = *reinterpret_cast<const bf16x8*>(&WNI[(size_t)(jt * 2 + ks) * 512 + lane * 8]);
            #pragma unroll
            for (int ks = 0; ks < 7; ++ks)
                wNh[ks] = *reinterpret_cast<const bf16x8*>(&WNH[(size_t)(jt * 7 + ks) * 512 + lane * 8]);

            // accumulators seeded with composed biases
            f32x4 aR[2], aZ[2], aNi[2], aNh[2];
            #pragma unroll
            for (int mt = 0; mt < 2; ++mt) {
                aR[mt]  = (f32x4){brv[ji], brv[ji], brv[ji], brv[ji]};
                aZ[mt]  = (f32x4){bzv[ji], bzv[ji], bzv[ji], bzv[ji]};
                aNi[mt] = (f32x4){biv[ji], biv[ji], biv[ji], biv[ji]};
                aNh[mt] = (f32x4){bhv[ji], bhv[ji], bhv[ji], bhv[ji]};
            }
            #pragma unroll
            for (int ks = 0; ks < 9; ++ks) {
                #pragma unroll
                for (int mt = 0; mt < 2; ++mt) {
                    bf16x8 a = (ks < 2)
                        ? *reinterpret_cast<const bf16x8*>(&SAb[(mt * 2 + ks) * 512 + lane * 8])
                        : *reinterpret_cast<const bf16x8*>(&Hb[cur][(mt * 7 + (ks - 2)) * 512 + lane * 8]);
                    aR[mt] = MFMA(a, wRr[ks], aR[mt]);
                    aZ[mt] = MFMA(a, wZr[ks], aZ[mt]);
                    if (ks < 2) aNi[mt] = MFMA(a, wNi[ks], aNi[mt]);
                    else        aNh[mt] = MFMA(a, wNh[ks - 2], aNh[mt]);
                }
            }
            // elementwise + h_new
            const int j = jt * 16 + col;
            const bool jv = (j < 200);
            #pragma unroll
            for (int mt = 0; mt < 2; ++mt) {
                #pragma unroll
                for (int q = 0; q < 4; ++q) {
                    const int r0 = kg * 4 + q;
                    const int slot = (j >> 5) * 512 + fragSlot(r0, j);
                    float rg = sigmf(aR[mt][q]);
                    float zg = sigmf(aZ[mt][q]);
                    float ng = tanh_fast(aNi[mt][q] + rg * aNh[mt][q]);
                    if (jv) {
                        float hv = b2f(Hb[cur][mt * 7 * 512 + slot]);
                        float hn = (1.f - zg) * ng + zg * hv;
                        Hb[nxt][mt * 7 * 512 + slot] = f2b(hn);
                        STG_S[(mt * 16 + r0) * 200 + j] = hn;
                    }
                }
            }
        }
        __syncthreads();

        // ---------- Phase B: hid = relu(h_new @ W1^T + b1) -> HIDb ----------
        #pragma unroll
        for (int ji = 0; ji < 2; ++ji) {
            const int jt = ji ? jt1 : jt0;
            if (jt < 0) continue;
            bf16x8 wb[7];
            #pragma unroll
            for (int ks = 0; ks < 7; ++ks)
                wb[ks] = *reinterpret_cast<const bf16x8*>(&W1w[(size_t)(jt * 7 + ks) * 512 + lane * 8]);
            f32x4 c0 = {0.f,0.f,0.f,0.f}, c1 = {0.f,0.f,0.f,0.f};
            #pragma unroll
            for (int ks = 0; ks < 7; ++ks) {
                bf16x8 a0 = *reinterpret_cast<const bf16x8*>(&Hb[nxt][(0 * 7 + ks) * 512 + lane * 8]);
                bf16x8 a1 = *reinterpret_cast<const bf16x8*>(&Hb[nxt][(1 * 7 + ks) * 512 + lane * 8]);
                c0 = MFMA(a0, wb[ks], c0);
                c1 = MFMA(a1, wb[ks], c1);
            }
            const int j = jt * 16 + col;
            #pragma unroll
            for (int q = 0; q < 4; ++q) {
                HIDb[(0 * 7 + (j >> 5)) * 512 + fragSlot(kg * 4 + q, j)] = f2b(fmaxf(c0[q] + b1v[ji], 0.f));
                HIDb[(1 * 7 + (j >> 5)) * 512 + fragSlot(kg * 4 + q, j)] = f2b(fmaxf(c1[q] + b1v[ji], 0.f));
            }
        }
        __syncthreads();

        // ---------- Phase C: waves 0-3 mu/var -> s_new ; waves 4-7 drain outputs + prefetch a ----------
        if (w < 4) {
            const int mt = w >> 1, ntile = w & 1;
            bf16x8 wm[7], wv[7];
            #pragma unroll
            for (int ks = 0; ks < 7; ++ks) {
                wm[ks] = *reinterpret_cast<const bf16x8*>(&WMV[(size_t)(ntile * 7 + ks) * 512 + lane * 8]);
                wv[ks] = *reinterpret_cast<const bf16x8*>(&WMV[(size_t)((2 + ntile) * 7 + ks) * 512 + lane * 8]);
            }
            f32x4 cm = {0.f,0.f,0.f,0.f}, cv = {0.f,0.f,0.f,0.f};
            #pragma unroll
            for (int ks = 0; ks < 7; ++ks) {
                bf16x8 a = *reinterpret_cast<const bf16x8*>(&HIDb[(mt * 7 + ks) * 512 + lane * 8]);
                cm = MFMA(a, wm[ks], cm);
                cv = MFMA(a, wv[ks], cv);
            }
            const int jm = ntile * 16 + col;
            const bool jmv = (jm < 30);
            #pragma unroll
            for (int q = 0; q < 4; ++q) {
                const int r0 = kg * 4 + q;
                const int row = mt * 16 + r0;
                float mu = cm[q] + bmuv;
                float vr = cv[q] + bvav;
                float var = ((vr > 20.f) ? vr : log1pf(__expf(vr))) + 0.1f;
                if (jmv) {
                    float eps = ld_nt(&noise[((size_t)t * BATCH + brow0 + row) * 30 + jm]);
                    float sn = mu + var * eps;
                    STG_Z[t & 1][row * 30 + jm] = sn;
                    SAb[(mt * 2) * 512 + fragSlot(r0, jm)] = f2b(sn);
                }
            }
        } else {
            const int di = (w - 4) * 64 + lane;   // 0..255
            // drain states(t): 1600 float4 full-line nt stores
            float* dst = out_states + ((size_t)t * BATCH + brow0) * 200;
            for (int i = di; i < 1600; i += 256) {
                f32x4 v = *reinterpret_cast<const f32x4*>(&STG_S[i * 4]);
                st_nt4(dst + i * 4, v);
            }
            // drain stoch(t-1): 240 float4
            if (t >= 1 && di < 240) {
                f32x4 v = *reinterpret_cast<const f32x4*>(&STG_Z[(t - 1) & 1][di * 4]);
                st_nt4(out_stoch + ((size_t)(t - 1) * BATCH + brow0) * 30 + di * 4, v);
            }
            // prefetch actions(t+1)
            if (t + 1 < T_STEPS && di < ROWS * 6) {
                const int r = di / 6, c = di % 6, k = 30 + c;
                float av = ld_nt(&actions[((size_t)(t + 1) * BATCH + brow0 + r) * 6 + c]);
                SAb[((r >> 4) * 2 + (k >> 5)) * 512 + fragSlot(r & 15, k)] = f2b(av);
            }
        }
        __syncthreads();
    }

    // drain stoch(T-1)
    if (tid < 240) {
        f32x4 v = *reinterpret_cast<const f32x4*>(&STG_Z[(T_STEPS - 1) & 1][tid * 4]);
        st_nt4(out_stoch + ((size_t)(T_STEPS - 1) * BATCH + brow0) * 30 + tid * 4, v);
    }
}

extern "C" void kernel_launch(void* const* d_in, const int* in_sizes, int n_in,
                              void* d_out, int out_size, void* d_ws, size_t ws_size,
                              hipStream_t stream)
{
    const float* actions = (const float*)d_in[0];
    const float* h0      = (const float*)d_in[1];
    const float* s0      = (const float*)d_in[2];
    const float* noise   = (const float*)d_in[3];
    const float* Wfc     = (const float*)d_in[4];
    const float* bfc     = (const float*)d_in[5];
    const float* Wih     = (const float*)d_in[6];
    const float* bih     = (const float*)d_in[7];
    const float* Whh     = (const float*)d_in[8];
    const float* bhh     = (const float*)d_in[9];
    const float* W1      = (const float*)d_in[10];
    const float* b1      = (const float*)d_in[11];
    const float* Wmu     = (const float*)d_in[12];
    const float* bmu     = (const float*)d_in[13];
    const float* Wvar    = (const float*)d_in[14];
    const float* bvar    = (const float*)d_in[15];

    unsigned short* wbuf = (unsigned short*)d_ws;

    rssm_prep<<<(W_TOTAL + 255) / 256, 256, 0, stream>>>(Wfc, Wih, Whh, W1, Wmu, Wvar, wbuf);
    rssm_main<<<NBLK, THREADS, 0, stream>>>(actions, h0, s0, noise, Wih, bfc, bih, bhh,
                                            b1, bmu, bvar, wbuf, (float*)d_out);
}